// Round 9
// baseline (686.489 us; speedup 1.0000x reference)
//
#include <hip/hip_runtime.h>

#define N_NODES 50000
#define DIM 128
#define N_LAYERS 5
#define BN_EPS 1e-5f

typedef __attribute__((ext_vector_type(8))) short short8;
typedef __attribute__((ext_vector_type(4))) float f32x4;

__device__ __forceinline__ float bf2f(unsigned int u16) {
    union { unsigned int i; float f; } c; c.i = u16 << 16; return c.f;
}
__device__ __forceinline__ unsigned short f2bf(float f) {
    union { float f; unsigned int i; } c; c.f = f;
    unsigned int v = c.i + 0x7FFFu + ((c.i >> 16) & 1u);   // RNE
    return (unsigned short)(v >> 16);
}

// ---------------- CSR build ----------------

__global__ void hist_kernel(const int* __restrict__ dst, int n_edges, int* __restrict__ counts) {
    int e = blockIdx.x * 256 + threadIdx.x;
    if (e < n_edges) atomicAdd(&counts[dst[e]], 1);
}

__global__ void scan_local(const int* __restrict__ counts, int n,
                           int* __restrict__ offsets, int* __restrict__ blocksums) {
    __shared__ int temp[256];
    int t = threadIdx.x;
    int i = blockIdx.x * 256 + t;
    int v = (i < n) ? counts[i] : 0;
    temp[t] = v;
    __syncthreads();
    for (int off = 1; off < 256; off <<= 1) {
        int add = (t >= off) ? temp[t - off] : 0;
        __syncthreads();
        temp[t] += add;
        __syncthreads();
    }
    if (i < n) offsets[i] = temp[t] - v;
    if (t == 255) blocksums[blockIdx.x] = temp[255];
}

__global__ void scan_block(int* __restrict__ blocksums, int nb) {
    __shared__ int temp[256];
    int t = threadIdx.x;
    int v = (t < nb) ? blocksums[t] : 0;
    temp[t] = v;
    __syncthreads();
    for (int off = 1; off < 256; off <<= 1) {
        int add = (t >= off) ? temp[t - off] : 0;
        __syncthreads();
        temp[t] += add;
        __syncthreads();
    }
    if (t < nb) blocksums[t] = temp[t] - v;
}

__global__ void scan_add(int* __restrict__ offsets, int* __restrict__ cursor,
                         const int* __restrict__ blocksums, int n, int n_edges) {
    int i = blockIdx.x * 256 + threadIdx.x;
    if (i < n) {
        int val = offsets[i] + blocksums[blockIdx.x];
        offsets[i] = val;
        cursor[i] = val;
    }
    if (i == 0) offsets[n] = n_edges;
}

__global__ void scatter_kernel(const int* __restrict__ src, const int* __restrict__ dst,
                               int n_edges, int* __restrict__ cursor, int* __restrict__ csr_src) {
    int e = blockIdx.x * 256 + threadIdx.x;
    if (e < n_edges) {
        int p = atomicAdd(&cursor[dst[e]], 1);
        csr_src[p] = src[e];
    }
}

// ---------------- prep ----------------

// pack W1/W2 (all layers) into MFMA B-fragment order, hi+lo bf16 planes.
__global__ void wpack_prep(const float* __restrict__ W1, const float* __restrict__ W2,
                           unsigned short* __restrict__ wp) {
    int idx = blockIdx.x * 256 + threadIdx.x;
    if (idx >= N_LAYERS * 2 * 16384) return;
    int j    = idx & 7;
    int lane = (idx >> 3) & 63;
    int nt   = (idx >> 9) & 7;
    int ks   = (idx >> 12) & 3;
    int mat  = (idx >> 14) & 1;
    int lay  = idx >> 15;
    int l15 = lane & 15, l4 = lane >> 4;
    int col = nt * 16 + l15;
    int kp = ks * 32 + l4 * 8 + j;
    int k = mat ? ((kp & 7) * 16 + (kp >> 3)) : kp;
    const float* W = mat ? W2 : W1;
    float w = W[((size_t)lay * 128 + k) * 128 + col];
    unsigned short hi = f2bf(w);
    unsigned short lo = f2bf(w - bf2f(hi));
    size_t base = (size_t)(lay * 2 + mat) * 32768;
    size_t inner = (size_t)((ks * 8 + nt) * 64 + lane) * 8 + j;
    wp[base + inner] = hi;
    wp[base + 16384 + inner] = lo;
}

// ---------------- fused agg + MLP ----------------
// Wave-private pipeline: wave w of each 256-thread block owns rows
// [blk*64 + w*16, +16). Phase A: full-wave-per-node gather-aggregate
// (depth-16 pipeline), hi/lo bf16 split into XOR-swizzled LDS planes.
// Phase B: GEMM1 (A-frags read from own rows, held in regs), mid
// overwrites the same LDS rows (same swizzle; (row&7) invariant since
// wave base is a multiple of 16). Phase C: GEMM2, store + BN partials.
// Only one __syncthreads (cross-wave partial reduce at the end).
template<int FP32IN>
__global__ __launch_bounds__(256) void agg_mlp(
        const void* __restrict__ xin,           // fp32 [N][128] or bf16-packed [N][64] uints
        const int* __restrict__ csr_src, const int* __restrict__ offsets,
        const short8* __restrict__ wp1, const float* __restrict__ b1,
        const short8* __restrict__ wp2, const float* __restrict__ b2,
        float* __restrict__ h_raw,
        float* __restrict__ part_s, float* __restrict__ part_q) {
    __shared__ __align__(16) char smem[64 * 256 * 2];   // 32KB: hi plane, lo plane
    __shared__ float red_s[4][128], red_q[4][128];
    char* hi_pl = smem;
    char* lo_pl = smem + 64 * 256;

    int t = threadIdx.x, w = t >> 6, l = t & 63;
    int l15 = l & 15, l4 = l >> 4;
    int row_base = blockIdx.x * 64 + w * 16;

    // ---- phase A: aggregate 16 nodes ----
    for (int n = 0; n < 16; ++n) {
        int nd = min(row_base + n, N_NODES - 1);
        int beg = offsets[nd], end = offsets[nd + 1];
        float ax, ay;
        if (FP32IN) {
            float2 u = ((const float2*)xin)[(size_t)nd * 64 + l];
            ax = u.x; ay = u.y;
        } else {
            unsigned int u = ((const unsigned int*)xin)[(size_t)nd * 64 + l];
            ax = bf2f(u & 0xFFFFu); ay = bf2f(u >> 16);
        }
        for (int e = beg; e < end; e += 16) {
            int s[16];
#pragma unroll
            for (int i = 0; i < 16; ++i) s[i] = csr_src[min(e + i, end - 1)];
            if (FP32IN) {
                float2 v[16];
#pragma unroll
                for (int i = 0; i < 16; ++i) v[i] = ((const float2*)xin)[(size_t)s[i] * 64 + l];
#pragma unroll
                for (int i = 0; i < 16; ++i) {
                    float wm = (e + i < end) ? 1.0f : 0.0f;
                    ax = fmaf(v[i].x, wm, ax);
                    ay = fmaf(v[i].y, wm, ay);
                }
            } else {
                unsigned int v[16];
#pragma unroll
                for (int i = 0; i < 16; ++i) v[i] = ((const unsigned int*)xin)[(size_t)s[i] * 64 + l];
#pragma unroll
                for (int i = 0; i < 16; ++i) {
                    float wm = (e + i < end) ? 1.0f : 0.0f;
                    ax = fmaf(bf2f(v[i] & 0xFFFFu), wm, ax);
                    ay = fmaf(bf2f(v[i] >> 16), wm, ay);
                }
            }
        }
        unsigned short hx = f2bf(ax), hy = f2bf(ay);
        unsigned short lx = f2bf(ax - bf2f(hx)), ly = f2bf(ay - bf2f(hy));
        int r = w * 16 + n;
        int off = r * 256 + ((l * 4) ^ ((r & 7) << 4));
        *(unsigned int*)(hi_pl + off) = (unsigned int)hx | ((unsigned int)hy << 16);
        *(unsigned int*)(lo_pl + off) = (unsigned int)lx | ((unsigned int)ly << 16);
    }

    // ---- phase B: GEMM1 (A-frags into regs BEFORE mid overwrites) ----
    short8 ah[4], al[4];
    {
        int r = w * 16 + l15;
#pragma unroll
        for (int ks = 0; ks < 4; ++ks) {
            int off = r * 256 + ((ks * 64 + l4 * 16) ^ ((l15 & 7) << 4));
            ah[ks] = *(const short8*)(hi_pl + off);
            al[ks] = *(const short8*)(lo_pl + off);
        }
    }

    const short8* wp1l = wp1 + 2048;   // lo plane of W1
    const short8* wp2l = wp2 + 2048;   // lo plane of W2

    f32x4 acc[8];
#pragma unroll
    for (int nt = 0; nt < 8; ++nt) acc[nt] = (f32x4)0.0f;
#pragma unroll
    for (int ks = 0; ks < 4; ++ks) {
#pragma unroll
        for (int nt = 0; nt < 8; ++nt) {
            short8 whi = wp1[(ks * 8 + nt) * 64 + l];
            short8 wlo = wp1l[(ks * 8 + nt) * 64 + l];
            acc[nt] = __builtin_amdgcn_mfma_f32_16x16x32_bf16(ah[ks], whi, acc[nt], 0, 0, 0);
            acc[nt] = __builtin_amdgcn_mfma_f32_16x16x32_bf16(al[ks], whi, acc[nt], 0, 0, 0);
            acc[nt] = __builtin_amdgcn_mfma_f32_16x16x32_bf16(ah[ks], wlo, acc[nt], 0, 0, 0);
        }
    }

    float b1v[8];
#pragma unroll
    for (int nt = 0; nt < 8; ++nt) b1v[nt] = b1[nt * 16 + l15];

    // bias + ReLU + hi/lo split; mid overwrites this wave's own rows
    // (k-permuted pack: byte l15*16 + 2*nt -> kp = l15*8+nt, matches wp2)
#pragma unroll
    for (int rr = 0; rr < 4; ++rr) {
        int row = l4 * 4 + rr;
        short8 ph, pl;
#pragma unroll
        for (int nt = 0; nt < 8; ++nt) {
            float v = fmaxf(acc[nt][rr] + b1v[nt], 0.0f);
            unsigned short hv = f2bf(v);
            ph[nt] = (short)hv;
            pl[nt] = (short)f2bf(v - bf2f(hv));
        }
        int off = (w * 16 + row) * 256 + ((l15 * 16) ^ ((row & 7) << 4));
        *(short8*)(hi_pl + off) = ph;
        *(short8*)(lo_pl + off) = pl;
    }

    // ---- phase C: GEMM2 ----
    {
        int r = w * 16 + l15;
#pragma unroll
        for (int ks = 0; ks < 4; ++ks) {
            int off = r * 256 + ((ks * 64 + l4 * 16) ^ ((l15 & 7) << 4));
            ah[ks] = *(const short8*)(hi_pl + off);
            al[ks] = *(const short8*)(lo_pl + off);
        }
    }
#pragma unroll
    for (int nt = 0; nt < 8; ++nt) acc[nt] = (f32x4)0.0f;
#pragma unroll
    for (int ks = 0; ks < 4; ++ks) {
#pragma unroll
        for (int nt = 0; nt < 8; ++nt) {
            short8 whi = wp2[(ks * 8 + nt) * 64 + l];
            short8 wlo = wp2l[(ks * 8 + nt) * 64 + l];
            acc[nt] = __builtin_amdgcn_mfma_f32_16x16x32_bf16(ah[ks], whi, acc[nt], 0, 0, 0);
            acc[nt] = __builtin_amdgcn_mfma_f32_16x16x32_bf16(al[ks], whi, acc[nt], 0, 0, 0);
            acc[nt] = __builtin_amdgcn_mfma_f32_16x16x32_bf16(ah[ks], wlo, acc[nt], 0, 0, 0);
        }
    }

    float b2v[8];
#pragma unroll
    for (int nt = 0; nt < 8; ++nt) b2v[nt] = b2[nt * 16 + l15];

    float s[8], q[8];
#pragma unroll
    for (int nt = 0; nt < 8; ++nt) { s[nt] = 0.0f; q[nt] = 0.0f; }

#pragma unroll
    for (int rr = 0; rr < 4; ++rr) {
        int rg = row_base + l4 * 4 + rr;
        bool ok = rg < N_NODES;
#pragma unroll
        for (int nt = 0; nt < 8; ++nt) {
            float v = fmaxf(acc[nt][rr] + b2v[nt], 0.0f);   // outer ReLU
            if (ok) {
                h_raw[(size_t)rg * 128 + nt * 16 + l15] = v;
                s[nt] += v;
                q[nt] += v * v;
            }
        }
    }
#pragma unroll
    for (int nt = 0; nt < 8; ++nt) {
        s[nt] += __shfl_xor(s[nt], 16); s[nt] += __shfl_xor(s[nt], 32);
        q[nt] += __shfl_xor(q[nt], 16); q[nt] += __shfl_xor(q[nt], 32);
    }
    if (l4 == 0) {
#pragma unroll
        for (int nt = 0; nt < 8; ++nt) {
            red_s[w][nt * 16 + l15] = s[nt];
            red_q[w][nt * 16 + l15] = q[nt];
        }
    }
    __syncthreads();
    if (t < 128) {
        part_s[blockIdx.x * 128 + t] = red_s[0][t] + red_s[1][t] + red_s[2][t] + red_s[3][t];
        part_q[blockIdx.x * 128 + t] = red_q[0][t] + red_q[1][t] + red_q[2][t] + red_q[3][t];
    }
}

// 256 blocks: block b reduces channel (b&127) of (b>>7 ? part_q : part_s)
__global__ __launch_bounds__(256) void bn_reduce(
        const float* __restrict__ part_s, const float* __restrict__ part_q,
        float* __restrict__ bn_sum, float* __restrict__ bn_sq, int nparts) {
    __shared__ float red[256];
    int c = blockIdx.x & 127;
    const float* src = (blockIdx.x >> 7) ? part_q : part_s;
    float* dst = (blockIdx.x >> 7) ? bn_sq : bn_sum;
    float a = 0.0f;
    for (int p = threadIdx.x; p < nparts; p += 256) a += src[p * 128 + c];
    red[threadIdx.x] = a;
    __syncthreads();
    for (int s = 128; s > 0; s >>= 1) {
        if (threadIdx.x < s) red[threadIdx.x] += red[threadIdx.x + s];
        __syncthreads();
    }
    if (threadIdx.x == 0) dst[c] = red[0];
}

// normalize in place (fp32); optionally emit bf16 next-layer input and/or fp32 dup
__global__ void bn_apply(float* __restrict__ h,
                         const float* __restrict__ bn_sum, const float* __restrict__ bn_sq,
                         const float* __restrict__ gamma, const float* __restrict__ beta,
                         uint2* __restrict__ xbf_next, float4* __restrict__ dup) {
    int i4 = blockIdx.x * 256 + threadIdx.x;
    if (i4 >= N_NODES * DIM / 4) return;
    float4 v = ((const float4*)h)[i4];
    int c0 = (i4 & 31) * 4;
    const float invN = 1.0f / (float)N_NODES;
    float* vp = (float*)&v;
#pragma unroll
    for (int j = 0; j < 4; ++j) {
        int c = c0 + j;
        float mean = bn_sum[c] * invN;
        float var = fmaxf(bn_sq[c] * invN - mean * mean, 0.0f);
        float inv = rsqrtf(var + BN_EPS);
        vp[j] = (vp[j] - mean) * inv * gamma[c] + beta[c];
    }
    ((float4*)h)[i4] = v;
    if (xbf_next) {
        unsigned int lo = (unsigned int)f2bf(vp[0]) | ((unsigned int)f2bf(vp[1]) << 16);
        unsigned int hi = (unsigned int)f2bf(vp[2]) | ((unsigned int)f2bf(vp[3]) << 16);
        xbf_next[i4] = make_uint2(lo, hi);
    }
    if (dup) dup[i4] = v;
}

// ---------------- launch ----------------

extern "C" void kernel_launch(void* const* d_in, const int* in_sizes, int n_in,
                              void* d_out, int out_size, void* d_ws, size_t ws_size,
                              hipStream_t stream) {
    const float* x     = (const float*)d_in[0];
    const int*   eidx  = (const int*)d_in[1];
    const float* W1    = (const float*)d_in[3];
    const float* b1    = (const float*)d_in[4];
    const float* W2    = (const float*)d_in[5];
    const float* b2    = (const float*)d_in[6];
    const float* gamma = (const float*)d_in[7];
    const float* beta  = (const float*)d_in[8];

    int n_edges = in_sizes[1] / 2;
    const int* src = eidx;
    const int* dst = eidx + n_edges;

    const int NBLK = (N_NODES + 63) / 64;    // 782 fused blocks

    int* counts    = (int*)d_ws;                       // 50000
    int* offsets   = counts + N_NODES;                 // 50001
    int* cursor    = offsets + N_NODES + 1;            // 50000
    int* blocksums = cursor + N_NODES;                 // 256
    int* csr_src   = blocksums + 256;                  // n_edges
    float* part_s  = (float*)(csr_src + n_edges);      // NBLK*128
    float* part_q  = part_s + NBLK * 128;              // NBLK*128
    float* bn_sum  = part_q + NBLK * 128;              // 128
    float* bn_sq   = bn_sum + DIM;                     // 128
    size_t wp_off = (((size_t)(bn_sq + DIM) - (size_t)d_ws) + 15) & ~(size_t)15;
    unsigned short* wp = (unsigned short*)((char*)d_ws + wp_off);   // 5*2*32768 bf16 (hi+lo)
    // bf16 next-layer input (written by bn_apply for layers 0..3)
    uint2* x_bf2 = (uint2*)(wp + (size_t)N_LAYERS * 2 * 32768);     // [N][32] uint2 = 12.8 MB

    float* out = (float*)d_out;

    // CSR build
    hipMemsetAsync(counts, 0, N_NODES * sizeof(int), stream);
    hist_kernel<<<(n_edges + 255) / 256, 256, 0, stream>>>(dst, n_edges, counts);
    int nb = (N_NODES + 255) / 256;
    scan_local<<<nb, 256, 0, stream>>>(counts, N_NODES, offsets, blocksums);
    scan_block<<<1, 256, 0, stream>>>(blocksums, nb);
    scan_add<<<nb, 256, 0, stream>>>(offsets, cursor, blocksums, N_NODES, n_edges);
    scatter_kernel<<<(n_edges + 255) / 256, 256, 0, stream>>>(src, dst, n_edges, cursor, csr_src);

    wpack_prep<<<(N_LAYERS * 2 * 16384 + 255) / 256, 256, 0, stream>>>(W1, W2, wp);

    for (int i = 0; i < N_LAYERS; ++i) {
        float* layer_out = out + (size_t)(1 + i) * N_NODES * DIM;
        const short8* wp1 = (const short8*)(wp + (size_t)(i * 2) * 32768);
        const short8* wp2 = (const short8*)(wp + (size_t)(i * 2 + 1) * 32768);
        if (i == 0)
            agg_mlp<1><<<NBLK, 256, 0, stream>>>(
                x, csr_src, offsets, wp1, b1 + (size_t)i * DIM, wp2, b2 + (size_t)i * DIM,
                layer_out, part_s, part_q);
        else
            agg_mlp<0><<<NBLK, 256, 0, stream>>>(
                x_bf2, csr_src, offsets, wp1, b1 + (size_t)i * DIM, wp2, b2 + (size_t)i * DIM,
                layer_out, part_s, part_q);
        bn_reduce<<<256, 256, 0, stream>>>(part_s, part_q, bn_sum, bn_sq, NBLK);
        bn_apply<<<(N_NODES * DIM / 4 + 255) / 256, 256, 0, stream>>>(
            layer_out, bn_sum, bn_sq, gamma + (size_t)i * DIM, beta + (size_t)i * DIM,
            (i < N_LAYERS - 1) ? x_bf2 : (uint2*)nullptr,
            (i == N_LAYERS - 1) ? (float4*)out : (float4*)nullptr);
    }
}

// Round 10
// 537.543 us; speedup vs baseline: 1.2771x; 1.2771x over previous
//
#include <hip/hip_runtime.h>

#define N_NODES 50000
#define DIM 128
#define N_LAYERS 5
#define BN_EPS 1e-5f

typedef __attribute__((ext_vector_type(8))) short short8;
typedef __attribute__((ext_vector_type(4))) float f32x4;

__device__ __forceinline__ float bf2f(unsigned int u16) {
    union { unsigned int i; float f; } c; c.i = u16 << 16; return c.f;
}
__device__ __forceinline__ unsigned short f2bf(float f) {
    union { float f; unsigned int i; } c; c.f = f;
    unsigned int v = c.i + 0x7FFFu + ((c.i >> 16) & 1u);   // RNE
    return (unsigned short)(v >> 16);
}

// ---------------- CSR build ----------------

__global__ void hist_kernel(const int* __restrict__ dst, int n_edges, int* __restrict__ counts) {
    int e = blockIdx.x * 256 + threadIdx.x;
    if (e < n_edges) atomicAdd(&counts[dst[e]], 1);
}

__global__ void scan_local(const int* __restrict__ counts, int n,
                           int* __restrict__ offsets, int* __restrict__ blocksums) {
    __shared__ int temp[256];
    int t = threadIdx.x;
    int i = blockIdx.x * 256 + t;
    int v = (i < n) ? counts[i] : 0;
    temp[t] = v;
    __syncthreads();
    for (int off = 1; off < 256; off <<= 1) {
        int add = (t >= off) ? temp[t - off] : 0;
        __syncthreads();
        temp[t] += add;
        __syncthreads();
    }
    if (i < n) offsets[i] = temp[t] - v;
    if (t == 255) blocksums[blockIdx.x] = temp[255];
}

__global__ void scan_block(int* __restrict__ blocksums, int nb) {
    __shared__ int temp[256];
    int t = threadIdx.x;
    int v = (t < nb) ? blocksums[t] : 0;
    temp[t] = v;
    __syncthreads();
    for (int off = 1; off < 256; off <<= 1) {
        int add = (t >= off) ? temp[t - off] : 0;
        __syncthreads();
        temp[t] += add;
        __syncthreads();
    }
    if (t < nb) blocksums[t] = temp[t] - v;
}

__global__ void scan_add(int* __restrict__ offsets, int* __restrict__ cursor,
                         const int* __restrict__ blocksums, int n, int n_edges) {
    int i = blockIdx.x * 256 + threadIdx.x;
    if (i < n) {
        int val = offsets[i] + blocksums[blockIdx.x];
        offsets[i] = val;
        cursor[i] = val;
    }
    if (i == 0) offsets[n] = n_edges;
}

__global__ void scatter_kernel(const int* __restrict__ src, const int* __restrict__ dst,
                               int n_edges, int* __restrict__ cursor, int* __restrict__ csr_src) {
    int e = blockIdx.x * 256 + threadIdx.x;
    if (e < n_edges) {
        int p = atomicAdd(&cursor[dst[e]], 1);
        csr_src[p] = src[e];
    }
}

// ---------------- prep ----------------

// pack W1/W2 (all layers) into MFMA B-fragment order, hi+lo bf16 planes.
__global__ void wpack_prep(const float* __restrict__ W1, const float* __restrict__ W2,
                           unsigned short* __restrict__ wp) {
    int idx = blockIdx.x * 256 + threadIdx.x;
    if (idx >= N_LAYERS * 2 * 16384) return;
    int j    = idx & 7;
    int lane = (idx >> 3) & 63;
    int nt   = (idx >> 9) & 7;
    int ks   = (idx >> 12) & 3;
    int mat  = (idx >> 14) & 1;
    int lay  = idx >> 15;
    int l15 = lane & 15, l4 = lane >> 4;
    int col = nt * 16 + l15;
    int kp = ks * 32 + l4 * 8 + j;
    int k = mat ? ((kp & 7) * 16 + (kp >> 3)) : kp;
    const float* W = mat ? W2 : W1;
    float w = W[((size_t)lay * 128 + k) * 128 + col];
    unsigned short hi = f2bf(w);
    unsigned short lo = f2bf(w - bf2f(hi));
    size_t base = (size_t)(lay * 2 + mat) * 32768;
    size_t inner = (size_t)((ks * 8 + nt) * 64 + lane) * 8 + j;
    wp[base + inner] = hi;
    wp[base + 16384 + inner] = lo;
}

// ---------------- per-layer kernels ----------------

// layer-0 aggregation: fp32 float4 gathers, 2 edges/instr, depth-8 pipeline.
__global__ void agg_kernel(const float* __restrict__ x, const int* __restrict__ csr_src,
                           const int* __restrict__ offsets,
                           unsigned int* __restrict__ h_hi_u, unsigned int* __restrict__ h_lo_u) {
    int wave = threadIdx.x >> 6;
    int l = threadIdx.x & 63;
    int node = blockIdx.x * 4 + wave;
    if (node >= N_NODES) return;
    int half = l >> 5;
    int d4 = l & 31;
    int beg = offsets[node], end = offsets[node + 1];
    const float4* x4 = (const float4*)x;

    float4 acc = make_float4(0.f, 0.f, 0.f, 0.f);
    if (half == 0) acc = x4[(size_t)node * 32 + d4];

    for (int e = beg; e < end; e += 16) {
        int s[8];
#pragma unroll
        for (int i = 0; i < 8; ++i) s[i] = csr_src[min(e + 2 * i + half, end - 1)];
        float4 v[8];
#pragma unroll
        for (int i = 0; i < 8; ++i) v[i] = x4[(size_t)s[i] * 32 + d4];
#pragma unroll
        for (int i = 0; i < 8; ++i) {
            float w = (e + 2 * i + half < end) ? 1.0f : 0.0f;
            acc.x = fmaf(v[i].x, w, acc.x);
            acc.y = fmaf(v[i].y, w, acc.y);
            acc.z = fmaf(v[i].z, w, acc.z);
            acc.w = fmaf(v[i].w, w, acc.w);
        }
    }

    acc.x += __shfl_xor(acc.x, 32);
    acc.y += __shfl_xor(acc.y, 32);
    acc.z += __shfl_xor(acc.z, 32);
    acc.w += __shfl_xor(acc.w, 32);

    unsigned short h0 = f2bf(acc.x), h1 = f2bf(acc.y);
    unsigned short h2 = f2bf(acc.z), h3 = f2bf(acc.w);
    if (half == 0) {
        uint2 hv;
        hv.x = (unsigned int)h0 | ((unsigned int)h1 << 16);
        hv.y = (unsigned int)h2 | ((unsigned int)h3 << 16);
        ((uint2*)h_hi_u)[(size_t)node * 32 + d4] = hv;
    } else {
        unsigned short l0 = f2bf(acc.x - bf2f(h0)), l1 = f2bf(acc.y - bf2f(h1));
        unsigned short l2 = f2bf(acc.z - bf2f(h2)), l3 = f2bf(acc.w - bf2f(h3));
        uint2 lv;
        lv.x = (unsigned int)l0 | ((unsigned int)l1 << 16);
        lv.y = (unsigned int)l2 | ((unsigned int)l3 << 16);
        ((uint2*)h_lo_u)[(size_t)node * 32 + d4] = lv;
    }
}

// layers 1..4: bf16 quarter-wave gathers — 16 lanes x uint4 per 256B row,
// 4 edges per instruction, depth-8 batches = 32 edges in flight per wave.
__global__ void agg_bf_kernel(const uint4* __restrict__ xbf4, const int* __restrict__ csr_src,
                              const int* __restrict__ offsets,
                              unsigned int* __restrict__ h_hi_u, unsigned int* __restrict__ h_lo_u) {
    int wave = threadIdx.x >> 6;
    int l = threadIdx.x & 63;
    int node = blockIdx.x * 4 + wave;
    if (node >= N_NODES) return;
    int quarter = l >> 4;    // which edge of the 4
    int d = l & 15;          // uint4 chunk (8 bf16 cols: d*8 .. d*8+7)
    int beg = offsets[node], end = offsets[node + 1];

    float a[8];
#pragma unroll
    for (int j = 0; j < 8; ++j) a[j] = 0.0f;
    if (quarter == 0) {
        uint4 u = xbf4[(size_t)node * 16 + d];   // self term once
        a[0] = bf2f(u.x & 0xFFFFu); a[1] = bf2f(u.x >> 16);
        a[2] = bf2f(u.y & 0xFFFFu); a[3] = bf2f(u.y >> 16);
        a[4] = bf2f(u.z & 0xFFFFu); a[5] = bf2f(u.z >> 16);
        a[6] = bf2f(u.w & 0xFFFFu); a[7] = bf2f(u.w >> 16);
    }

    for (int e = beg; e < end; e += 32) {
        int s[8];
#pragma unroll
        for (int i = 0; i < 8; ++i) s[i] = csr_src[min(e + 4 * i + quarter, end - 1)];
        uint4 v[8];
#pragma unroll
        for (int i = 0; i < 8; ++i) v[i] = xbf4[(size_t)s[i] * 16 + d];
#pragma unroll
        for (int i = 0; i < 8; ++i) {
            float w = (e + 4 * i + quarter < end) ? 1.0f : 0.0f;
            a[0] = fmaf(bf2f(v[i].x & 0xFFFFu), w, a[0]);
            a[1] = fmaf(bf2f(v[i].x >> 16),     w, a[1]);
            a[2] = fmaf(bf2f(v[i].y & 0xFFFFu), w, a[2]);
            a[3] = fmaf(bf2f(v[i].y >> 16),     w, a[3]);
            a[4] = fmaf(bf2f(v[i].z & 0xFFFFu), w, a[4]);
            a[5] = fmaf(bf2f(v[i].z >> 16),     w, a[5]);
            a[6] = fmaf(bf2f(v[i].w & 0xFFFFu), w, a[6]);
            a[7] = fmaf(bf2f(v[i].w >> 16),     w, a[7]);
        }
    }

    // reduce across the 4 quarters (lanes l, l^16, l^32, l^48 share d)
#pragma unroll
    for (int j = 0; j < 8; ++j) {
        a[j] += __shfl_xor(a[j], 16);
        a[j] += __shfl_xor(a[j], 32);
    }

    unsigned short h[8];
#pragma unroll
    for (int j = 0; j < 8; ++j) h[j] = f2bf(a[j]);
    if (quarter == 0) {
        uint4 hv;
        hv.x = (unsigned int)h[0] | ((unsigned int)h[1] << 16);
        hv.y = (unsigned int)h[2] | ((unsigned int)h[3] << 16);
        hv.z = (unsigned int)h[4] | ((unsigned int)h[5] << 16);
        hv.w = (unsigned int)h[6] | ((unsigned int)h[7] << 16);
        ((uint4*)h_hi_u)[(size_t)node * 16 + d] = hv;
    } else if (quarter == 1) {
        unsigned short lo[8];
#pragma unroll
        for (int j = 0; j < 8; ++j) lo[j] = f2bf(a[j] - bf2f(h[j]));
        uint4 lv;
        lv.x = (unsigned int)lo[0] | ((unsigned int)lo[1] << 16);
        lv.y = (unsigned int)lo[2] | ((unsigned int)lo[3] << 16);
        lv.z = (unsigned int)lo[4] | ((unsigned int)lo[5] << 16);
        lv.w = (unsigned int)lo[6] | ((unsigned int)lo[7] << 16);
        ((uint4*)h_lo_u)[(size_t)node * 16 + d] = lv;
    }
}

// fused MFMA MLP (bf16x2 split, 3-product): ReLU(h@W1+b1)@W2+b2 -> ReLU
// -> h_raw (fp32) + per-block BN partials
__global__ __launch_bounds__(128) void mlp_mfma(
        const unsigned short* __restrict__ h_hi, const unsigned short* __restrict__ h_lo,
        const short8* __restrict__ wp1, const float* __restrict__ b1,
        const short8* __restrict__ wp2, const float* __restrict__ b2,
        float* __restrict__ h_raw,
        float* __restrict__ part_s, float* __restrict__ part_q) {
    __shared__ unsigned short mid_hi[2][2][16][128];   // [wave][m][row][kp], XOR-swizzled
    __shared__ unsigned short mid_lo[2][2][16][128];
    __shared__ float red_s[2][128], red_q[2][128];
    int t = threadIdx.x, wave = t >> 6, l = t & 63;
    int l15 = l & 15, l4 = l >> 4;
    int row_base = blockIdx.x * 64 + wave * 32;

    int r0 = row_base + l15, r1 = r0 + 16;
    int cr0 = min(r0, N_NODES - 1), cr1 = min(r1, N_NODES - 1);
    const short8* ah0p = (const short8*)(h_hi + (size_t)cr0 * 128);
    const short8* ah1p = (const short8*)(h_hi + (size_t)cr1 * 128);
    const short8* al0p = (const short8*)(h_lo + (size_t)cr0 * 128);
    const short8* al1p = (const short8*)(h_lo + (size_t)cr1 * 128);

    const short8* wp1l = wp1 + 2048;   // lo plane
    const short8* wp2l = wp2 + 2048;

    f32x4 acc[2][8];
#pragma unroll
    for (int m = 0; m < 2; ++m)
#pragma unroll
        for (int nt = 0; nt < 8; ++nt) acc[m][nt] = (f32x4)0.0f;

#pragma unroll
    for (int ks = 0; ks < 4; ++ks) {
        short8 ah0 = ah0p[ks * 4 + l4];
        short8 ah1 = ah1p[ks * 4 + l4];
        short8 al0 = al0p[ks * 4 + l4];
        short8 al1 = al1p[ks * 4 + l4];
#pragma unroll
        for (int nt = 0; nt < 8; ++nt) {
            short8 whi = wp1[(ks * 8 + nt) * 64 + l];
            short8 wlo = wp1l[(ks * 8 + nt) * 64 + l];
            acc[0][nt] = __builtin_amdgcn_mfma_f32_16x16x32_bf16(ah0, whi, acc[0][nt], 0, 0, 0);
            acc[0][nt] = __builtin_amdgcn_mfma_f32_16x16x32_bf16(al0, whi, acc[0][nt], 0, 0, 0);
            acc[0][nt] = __builtin_amdgcn_mfma_f32_16x16x32_bf16(ah0, wlo, acc[0][nt], 0, 0, 0);
            acc[1][nt] = __builtin_amdgcn_mfma_f32_16x16x32_bf16(ah1, whi, acc[1][nt], 0, 0, 0);
            acc[1][nt] = __builtin_amdgcn_mfma_f32_16x16x32_bf16(al1, whi, acc[1][nt], 0, 0, 0);
            acc[1][nt] = __builtin_amdgcn_mfma_f32_16x16x32_bf16(ah1, wlo, acc[1][nt], 0, 0, 0);
        }
    }

    float b1v[8];
#pragma unroll
    for (int nt = 0; nt < 8; ++nt) b1v[nt] = b1[nt * 16 + l15];

#pragma unroll
    for (int m = 0; m < 2; ++m) {
#pragma unroll
        for (int rr = 0; rr < 4; ++rr) {
            int row = l4 * 4 + rr;
            short8 ph, pl;
#pragma unroll
            for (int nt = 0; nt < 8; ++nt) {
                float v = fmaxf(acc[m][nt][rr] + b1v[nt], 0.0f);
                unsigned short hv = f2bf(v);
                ph[nt] = (short)hv;
                pl[nt] = (short)f2bf(v - bf2f(hv));
            }
            int off = (l15 * 16) ^ ((row & 7) << 4);
            *(short8*)((char*)&mid_hi[wave][m][row][0] + off) = ph;
            *(short8*)((char*)&mid_lo[wave][m][row][0] + off) = pl;
        }
    }
    __syncthreads();

    f32x4 acc2[2][8];
#pragma unroll
    for (int m = 0; m < 2; ++m)
#pragma unroll
        for (int nt = 0; nt < 8; ++nt) acc2[m][nt] = (f32x4)0.0f;

#pragma unroll
    for (int ks = 0; ks < 4; ++ks) {
        int off = (ks * 64 + l4 * 16) ^ ((l15 & 7) << 4);
        short8 ah0 = *(const short8*)((char*)&mid_hi[wave][0][l15][0] + off);
        short8 ah1 = *(const short8*)((char*)&mid_hi[wave][1][l15][0] + off);
        short8 al0 = *(const short8*)((char*)&mid_lo[wave][0][l15][0] + off);
        short8 al1 = *(const short8*)((char*)&mid_lo[wave][1][l15][0] + off);
#pragma unroll
        for (int nt = 0; nt < 8; ++nt) {
            short8 whi = wp2[(ks * 8 + nt) * 64 + l];
            short8 wlo = wp2l[(ks * 8 + nt) * 64 + l];
            acc2[0][nt] = __builtin_amdgcn_mfma_f32_16x16x32_bf16(ah0, whi, acc2[0][nt], 0, 0, 0);
            acc2[0][nt] = __builtin_amdgcn_mfma_f32_16x16x32_bf16(al0, whi, acc2[0][nt], 0, 0, 0);
            acc2[0][nt] = __builtin_amdgcn_mfma_f32_16x16x32_bf16(ah0, wlo, acc2[0][nt], 0, 0, 0);
            acc2[1][nt] = __builtin_amdgcn_mfma_f32_16x16x32_bf16(ah1, whi, acc2[1][nt], 0, 0, 0);
            acc2[1][nt] = __builtin_amdgcn_mfma_f32_16x16x32_bf16(al1, whi, acc2[1][nt], 0, 0, 0);
            acc2[1][nt] = __builtin_amdgcn_mfma_f32_16x16x32_bf16(ah1, wlo, acc2[1][nt], 0, 0, 0);
        }
    }

    float b2v[8];
#pragma unroll
    for (int nt = 0; nt < 8; ++nt) b2v[nt] = b2[nt * 16 + l15];

    float s[8], q[8];
#pragma unroll
    for (int nt = 0; nt < 8; ++nt) { s[nt] = 0.0f; q[nt] = 0.0f; }

#pragma unroll
    for (int m = 0; m < 2; ++m) {
#pragma unroll
        for (int rr = 0; rr < 4; ++rr) {
            int rg = row_base + m * 16 + l4 * 4 + rr;
            bool ok = rg < N_NODES;
#pragma unroll
            for (int nt = 0; nt < 8; ++nt) {
                float v = fmaxf(acc2[m][nt][rr] + b2v[nt], 0.0f);   // outer ReLU
                if (ok) {
                    h_raw[(size_t)rg * 128 + nt * 16 + l15] = v;
                    s[nt] += v;
                    q[nt] += v * v;
                }
            }
        }
    }
#pragma unroll
    for (int nt = 0; nt < 8; ++nt) {
        s[nt] += __shfl_xor(s[nt], 16); s[nt] += __shfl_xor(s[nt], 32);
        q[nt] += __shfl_xor(q[nt], 16); q[nt] += __shfl_xor(q[nt], 32);
    }
    if (l4 == 0) {
#pragma unroll
        for (int nt = 0; nt < 8; ++nt) {
            red_s[wave][nt * 16 + l15] = s[nt];
            red_q[wave][nt * 16 + l15] = q[nt];
        }
    }
    __syncthreads();
    if (t < 128) {
        part_s[blockIdx.x * 128 + t] = red_s[0][t] + red_s[1][t];
        part_q[blockIdx.x * 128 + t] = red_q[0][t] + red_q[1][t];
    }
}

// 256 blocks: block b reduces channel (b&127) of (b>>7 ? part_q : part_s)
__global__ __launch_bounds__(256) void bn_reduce(
        const float* __restrict__ part_s, const float* __restrict__ part_q,
        float* __restrict__ bn_sum, float* __restrict__ bn_sq, int nparts) {
    __shared__ float red[256];
    int c = blockIdx.x & 127;
    const float* src = (blockIdx.x >> 7) ? part_q : part_s;
    float* dst = (blockIdx.x >> 7) ? bn_sq : bn_sum;
    float a = 0.0f;
    for (int p = threadIdx.x; p < nparts; p += 256) a += src[p * 128 + c];
    red[threadIdx.x] = a;
    __syncthreads();
    for (int s = 128; s > 0; s >>= 1) {
        if (threadIdx.x < s) red[threadIdx.x] += red[threadIdx.x + s];
        __syncthreads();
    }
    if (threadIdx.x == 0) dst[c] = red[0];
}

// normalize in place (fp32); optionally emit bf16 next-layer input and/or fp32 dup
__global__ void bn_apply(float* __restrict__ h,
                         const float* __restrict__ bn_sum, const float* __restrict__ bn_sq,
                         const float* __restrict__ gamma, const float* __restrict__ beta,
                         uint2* __restrict__ xbf_next, float4* __restrict__ dup) {
    int i4 = blockIdx.x * 256 + threadIdx.x;
    if (i4 >= N_NODES * DIM / 4) return;
    float4 v = ((const float4*)h)[i4];
    int c0 = (i4 & 31) * 4;
    const float invN = 1.0f / (float)N_NODES;
    float* vp = (float*)&v;
#pragma unroll
    for (int j = 0; j < 4; ++j) {
        int c = c0 + j;
        float mean = bn_sum[c] * invN;
        float var = fmaxf(bn_sq[c] * invN - mean * mean, 0.0f);
        float inv = rsqrtf(var + BN_EPS);
        vp[j] = (vp[j] - mean) * inv * gamma[c] + beta[c];
    }
    ((float4*)h)[i4] = v;
    if (xbf_next) {
        unsigned int lo = (unsigned int)f2bf(vp[0]) | ((unsigned int)f2bf(vp[1]) << 16);
        unsigned int hi = (unsigned int)f2bf(vp[2]) | ((unsigned int)f2bf(vp[3]) << 16);
        xbf_next[i4] = make_uint2(lo, hi);
    }
    if (dup) dup[i4] = v;
}

// ---------------- launch ----------------

extern "C" void kernel_launch(void* const* d_in, const int* in_sizes, int n_in,
                              void* d_out, int out_size, void* d_ws, size_t ws_size,
                              hipStream_t stream) {
    const float* x     = (const float*)d_in[0];
    const int*   eidx  = (const int*)d_in[1];
    const float* W1    = (const float*)d_in[3];
    const float* b1    = (const float*)d_in[4];
    const float* W2    = (const float*)d_in[5];
    const float* b2    = (const float*)d_in[6];
    const float* gamma = (const float*)d_in[7];
    const float* beta  = (const float*)d_in[8];

    int n_edges = in_sizes[1] / 2;
    const int* src = eidx;
    const int* dst = eidx + n_edges;

    const int NBLK = (N_NODES + 63) / 64;    // 782 mlp blocks

    int* counts    = (int*)d_ws;                       // 50000
    int* offsets   = counts + N_NODES;                 // 50001
    int* cursor    = offsets + N_NODES + 1;            // 50000
    int* blocksums = cursor + N_NODES;                 // 256
    int* csr_src   = blocksums + 256;                  // n_edges
    float* part_s  = (float*)(csr_src + n_edges);      // NBLK*128
    float* part_q  = part_s + NBLK * 128;              // NBLK*128
    float* bn_sum  = part_q + NBLK * 128;              // 128
    float* bn_sq   = bn_sum + DIM;                     // 128
    size_t wp_off = (((size_t)(bn_sq + DIM) - (size_t)d_ws) + 15) & ~(size_t)15;
    unsigned short* wp = (unsigned short*)((char*)d_ws + wp_off);   // 5*2*32768 bf16 (hi+lo)
    // bf16 next-layer input (written by bn_apply for layers 0..3), 16B aligned
    size_t xb_off = (wp_off + (size_t)N_LAYERS * 2 * 32768 * 2 + 15) & ~(size_t)15;
    uint2* x_bf2 = (uint2*)((char*)d_ws + xb_off);                  // [N][32] uint2 = 12.8 MB

    float* out = (float*)d_out;
    // slot 0 doubles as bf16 hi/lo scratch until the last layer writes it
    unsigned int* h_hi_u = (unsigned int*)d_out;                    // [N][64] uints
    unsigned int* h_lo_u = h_hi_u + (size_t)N_NODES * 64;
    const unsigned short* h_hi = (const unsigned short*)h_hi_u;
    const unsigned short* h_lo = (const unsigned short*)h_lo_u;

    // CSR build
    hipMemsetAsync(counts, 0, N_NODES * sizeof(int), stream);
    hist_kernel<<<(n_edges + 255) / 256, 256, 0, stream>>>(dst, n_edges, counts);
    int nb = (N_NODES + 255) / 256;
    scan_local<<<nb, 256, 0, stream>>>(counts, N_NODES, offsets, blocksums);
    scan_block<<<1, 256, 0, stream>>>(blocksums, nb);
    scan_add<<<nb, 256, 0, stream>>>(offsets, cursor, blocksums, N_NODES, n_edges);
    scatter_kernel<<<(n_edges + 255) / 256, 256, 0, stream>>>(src, dst, n_edges, cursor, csr_src);

    wpack_prep<<<(N_LAYERS * 2 * 16384 + 255) / 256, 256, 0, stream>>>(W1, W2, wp);

    for (int i = 0; i < N_LAYERS; ++i) {
        float* layer_out = out + (size_t)(1 + i) * N_NODES * DIM;
        if (i == 0)
            agg_kernel<<<(N_NODES + 3) / 4, 256, 0, stream>>>(x, csr_src, offsets,
                                                              h_hi_u, h_lo_u);
        else
            agg_bf_kernel<<<(N_NODES + 3) / 4, 256, 0, stream>>>((const uint4*)x_bf2,
                                                                 csr_src, offsets,
                                                                 h_hi_u, h_lo_u);
        mlp_mfma<<<NBLK, 128, 0, stream>>>(
            h_hi, h_lo,
            (const short8*)(wp + (size_t)(i * 2) * 32768), b1 + (size_t)i * DIM,
            (const short8*)(wp + (size_t)(i * 2 + 1) * 32768), b2 + (size_t)i * DIM,
            layer_out, part_s, part_q);
        bn_reduce<<<256, 256, 0, stream>>>(part_s, part_q, bn_sum, bn_sq, NBLK);
        bn_apply<<<(N_NODES * DIM / 4 + 255) / 256, 256, 0, stream>>>(
            layer_out, bn_sum, bn_sq, gamma + (size_t)i * DIM, beta + (size_t)i * DIM,
            (i < N_LAYERS - 1) ? x_bf2 : (uint2*)nullptr,
            (i == N_LAYERS - 1) ? (float4*)out : (float4*)nullptr);
    }
}